// Round 5
// baseline (580.153 us; speedup 1.0000x reference)
//
#include <hip/hip_runtime.h>
#include <hip/hip_bf16.h>

// MHA forward: B=4, L=2048, D=1024, H=16, dk=64.
// Inputs float32 (+ int32 mask), OUTPUT FLOAT32 (reference output dtype).
// Internally bf16 MFMA with fp32 accumulation.
// Kernels: QKV proj GEMMs (NT, MFMA; V writes transposed layout); mask bit-pack;
// flash attention (online softmax); output proj GEMM -> f32 d_out.

typedef __hip_bfloat16 bf16;
typedef __attribute__((ext_vector_type(8))) short s8;   // 8 bf16 = 4 VGPRs (MFMA A/B frag)
typedef __attribute__((ext_vector_type(4))) short s4;   // 4 bf16 = 8B
typedef __attribute__((ext_vector_type(4))) float f4;   // MFMA C/D frag

constexpr int Bb = 4, Ls = 2048, Dd = 1024, Hh = 16, DK = 64;
constexpr int BHn = Bb * Hh;          // 64
constexpr int Mrows = Bb * Ls;        // 8192

__device__ __forceinline__ s8 ld8(const float* __restrict__ p) {
    const float4 a = *(const float4*)p;
    const float4 b = *(const float4*)(p + 4);
    union { bf16 h[8]; s8 v; } u;
    u.h[0] = __float2bfloat16(a.x); u.h[1] = __float2bfloat16(a.y);
    u.h[2] = __float2bfloat16(a.z); u.h[3] = __float2bfloat16(a.w);
    u.h[4] = __float2bfloat16(b.x); u.h[5] = __float2bfloat16(b.y);
    u.h[6] = __float2bfloat16(b.z); u.h[7] = __float2bfloat16(b.w);
    return u.v;
}
__device__ __forceinline__ s8 ld8(const bf16* __restrict__ p) {
    return *(const s8*)p;
}
__device__ __forceinline__ void st1(bf16* p, float v)  { *p = __float2bfloat16(v); }
__device__ __forceinline__ void st1(float* p, float v) { *p = v; }

// ---------------- NT GEMM: out[m][n] = sum_k A[m][k] * W[n][k] + bias[n] ----------------
// MODE 0: out row-major [M][N]                  (final projection -> f32 d_out)
// MODE 1: out headed [bh][l][d]                 (Q, K)
// MODE 2: out headed-transposed [bh][d][l]      (V)
template<int MODE, typename AT, typename OT>
__global__ __launch_bounds__(256) void gemm_nt_bias(
    const AT* __restrict__ A, const float* __restrict__ W,
    const float* __restrict__ bias, OT* __restrict__ out,
    int M, int N, int K)
{
    __shared__ __align__(16) bf16 lA[128 * 32];
    __shared__ __align__(16) bf16 lB[128 * 32];
    const int tid  = threadIdx.x;
    const int wave = tid >> 6, lane = tid & 63;
    const int qd = lane >> 4, lr = lane & 15;
    const int wm = (wave & 1) * 64, wn = (wave >> 1) * 64;   // 2x2 wave grid, 64x64 each
    const int row0 = blockIdx.x * 128, col0 = blockIdx.y * 128;

    f4 acc[4][4] = {};

    const int c0 = tid, c1 = tid + 256;                      // two 8-elem chunks per thread
    const int r0 = c0 >> 2, kc0 = (c0 & 3) * 8;
    const int r1 = c1 >> 2, kc1 = (c1 & 3) * 8;

    for (int kt = 0; kt < K; kt += 32) {
        *(s8*)&lA[c0 * 8] = ld8(A + (size_t)(row0 + r0) * K + kt + kc0);
        *(s8*)&lA[c1 * 8] = ld8(A + (size_t)(row0 + r1) * K + kt + kc1);
        *(s8*)&lB[c0 * 8] = ld8(W + (size_t)(col0 + r0) * K + kt + kc0);
        *(s8*)&lB[c1 * 8] = ld8(W + (size_t)(col0 + r1) * K + kt + kc1);
        __syncthreads();
        s8 af[4], bfm[4];
#pragma unroll
        for (int i = 0; i < 4; i++) af[i]  = *(const s8*)&lA[(wm + i * 16 + lr) * 32 + qd * 8];
#pragma unroll
        for (int j = 0; j < 4; j++) bfm[j] = *(const s8*)&lB[(wn + j * 16 + lr) * 32 + qd * 8];
#pragma unroll
        for (int i = 0; i < 4; i++)
#pragma unroll
            for (int j = 0; j < 4; j++)
                acc[i][j] = __builtin_amdgcn_mfma_f32_16x16x32_bf16(af[i], bfm[j], acc[i][j], 0, 0, 0);
        __syncthreads();
    }

    // epilogue: C/D layout col=lane&15, row=(lane>>4)*4+reg
#pragma unroll
    for (int j = 0; j < 4; j++) {
        const int colg = col0 + wn + j * 16 + lr;
        const float bv = bias[colg];
#pragma unroll
        for (int i = 0; i < 4; i++) {
            const int rowb = row0 + wm + i * 16 + qd * 4;   // 4 consecutive rows
            if (MODE == 2) {
                // V transposed: [bh][d][l]; rows -> l (consecutive), col -> (h,d)
                const int b = rowb >> 11, l = rowb & (Ls - 1);
                const int h = colg >> 6, d = colg & (DK - 1);
                union { bf16 h4[4]; s4 v; } u;
#pragma unroll
                for (int ri = 0; ri < 4; ri++)
                    u.h4[ri] = __float2bfloat16(acc[i][j][ri] + bv);
                *(s4*)&((bf16*)out)[(((size_t)(b * Hh + h) * DK) + d) * Ls + l] = u.v;
            } else {
#pragma unroll
                for (int ri = 0; ri < 4; ri++) {
                    const int rowg = rowb + ri;
                    const float v = acc[i][j][ri] + bv;
                    size_t idx;
                    if (MODE == 0) {
                        idx = (size_t)rowg * N + colg;
                    } else {
                        const int b = rowg >> 11, l = rowg & (Ls - 1);
                        const int h = colg >> 6, d = colg & (DK - 1);
                        idx = (((size_t)(b * Hh + h) * Ls) + l) * DK + d;
                    }
                    st1(&out[idx], v);
                }
            }
        }
    }
}

// ---------------- mask bit-pack: 64 int32 -> 1 uint64 via ballot ----------------
__global__ __launch_bounds__(256) void pack_mask(
    const int* __restrict__ m, unsigned long long* __restrict__ bits)
{
    const int g = blockIdx.x * 256 + threadIdx.x;
    const unsigned long long b = __ballot(m[g] != 0);
    if ((threadIdx.x & 63) == 0) bits[g >> 6] = b;
}

// ---------------- flash attention ----------------
// grid: BH * (L/64); block 256 = 4 waves; each wave owns 16 q-rows, full dk=64.
__global__ __launch_bounds__(256) void attn(
    const bf16* __restrict__ Q, const bf16* __restrict__ K,
    const bf16* __restrict__ Vt, const unsigned long long* __restrict__ mbits,
    bf16* __restrict__ X)
{
    __shared__ __align__(16) bf16 lQ[64 * 72];   // [q][d] pitch 72
    __shared__ __align__(16) bf16 lK[64 * 72];   // [k][d]
    __shared__ __align__(16) bf16 lV[64 * 72];   // [d][k]  (from pre-transposed Vt)
    __shared__ __align__(16) bf16 lP[4][16 * 72];// per-wave P tile [q][k]
    __shared__ unsigned long long lM[64];

    const int blk = blockIdx.x;
    const int bh = blk >> 5;
    const int q0 = (blk & 31) * 64;
    const int tid = threadIdx.x;
    const int wave = tid >> 6, lane = tid & 63;
    const int qd = lane >> 4, lr = lane & 15;

    const bf16* Qb = Q  + (size_t)bh * Ls * DK;
    const bf16* Kb = K  + (size_t)bh * Ls * DK;
    const bf16* Vb = Vt + (size_t)bh * DK * Ls;

    // stage Q tile once
    {
        const int r = tid >> 2, seg = (tid & 3) * 16;
        *(s8*)&lQ[r * 72 + seg]     = *(const s8*)(Qb + (size_t)(q0 + r) * DK + seg);
        *(s8*)&lQ[r * 72 + seg + 8] = *(const s8*)(Qb + (size_t)(q0 + r) * DK + seg + 8);
    }
    __syncthreads();
    s8 aq[2];
    aq[0] = *(const s8*)&lQ[(wave * 16 + lr) * 72 + qd * 8];
    aq[1] = *(const s8*)&lQ[(wave * 16 + lr) * 72 + 32 + qd * 8];

    f4 o[4] = {};
    float mrun[4], lrun[4];
#pragma unroll
    for (int i = 0; i < 4; i++) { mrun[i] = -3e38f; lrun[i] = 0.f; }
    const float scale = 0.125f;   // dk^-0.5

    for (int kt = 0; kt < Ls / 64; ++kt) {
        const int k0 = kt * 64;
        {   // stage K [k][d], V [d][k], mask words
            const int r = tid >> 2, seg = (tid & 3) * 16;
            *(s8*)&lK[r * 72 + seg]     = *(const s8*)(Kb + (size_t)(k0 + r) * DK + seg);
            *(s8*)&lK[r * 72 + seg + 8] = *(const s8*)(Kb + (size_t)(k0 + r) * DK + seg + 8);
            *(s8*)&lV[r * 72 + seg]     = *(const s8*)(Vb + (size_t)r * Ls + k0 + seg);
            *(s8*)&lV[r * 72 + seg + 8] = *(const s8*)(Vb + (size_t)r * Ls + k0 + seg + 8);
            if (tid < 64) lM[tid] = mbits[(size_t)(q0 + tid) * (Ls / 64) + kt];
        }
        __syncthreads();

        // S = Q K^T  (NT)
        f4 s[4] = {};
#pragma unroll
        for (int nt = 0; nt < 4; nt++) {
            s8 bk0 = *(const s8*)&lK[(nt * 16 + lr) * 72 + qd * 8];
            s8 bk1 = *(const s8*)&lK[(nt * 16 + lr) * 72 + 32 + qd * 8];
            s[nt] = __builtin_amdgcn_mfma_f32_16x16x32_bf16(aq[0], bk0, s[nt], 0, 0, 0);
            s[nt] = __builtin_amdgcn_mfma_f32_16x16x32_bf16(aq[1], bk1, s[nt], 0, 0, 0);
        }
        // scale + mask (masked_fill == 0 -> -1e9, matching ref)
#pragma unroll
        for (int ri = 0; ri < 4; ri++) {
            const unsigned long long w = lM[wave * 16 + qd * 4 + ri];
#pragma unroll
            for (int nt = 0; nt < 4; nt++) {
                float v = s[nt][ri] * scale;
                const int kbit = nt * 16 + lr;
                if (!((w >> kbit) & 1ULL)) v = -1e9f;
                s[nt][ri] = v;
            }
        }
        // online softmax per row (row lives on 16 lanes sharing qd)
        float alpha[4];
#pragma unroll
        for (int ri = 0; ri < 4; ri++) {
            float tm = fmaxf(fmaxf(s[0][ri], s[1][ri]), fmaxf(s[2][ri], s[3][ri]));
#pragma unroll
            for (int off = 1; off < 16; off <<= 1)
                tm = fmaxf(tm, __shfl_xor(tm, off, 64));
            const float mnew = fmaxf(mrun[ri], tm);
            alpha[ri] = __expf(mrun[ri] - mnew);
            mrun[ri] = mnew;
            float rs = 0.f;
#pragma unroll
            for (int nt = 0; nt < 4; nt++) {
                const float p = __expf(s[nt][ri] - mnew);
                s[nt][ri] = p;
                rs += p;
            }
#pragma unroll
            for (int off = 1; off < 16; off <<= 1)
                rs += __shfl_xor(rs, off, 64);
            lrun[ri] = lrun[ri] * alpha[ri] + rs;
        }
        // P -> LDS (C-layout scatter; A-layout gather)
#pragma unroll
        for (int ri = 0; ri < 4; ri++)
#pragma unroll
            for (int nt = 0; nt < 4; nt++)
                lP[wave][(qd * 4 + ri) * 72 + nt * 16 + lr] = __float2bfloat16(s[nt][ri]);
        __syncthreads();

        // O = O*alpha + P @ Vtile
#pragma unroll
        for (int nt = 0; nt < 4; nt++)
#pragma unroll
            for (int ri = 0; ri < 4; ri++)
                o[nt][ri] *= alpha[ri];
        s8 ap0 = *(const s8*)&lP[wave][lr * 72 + qd * 8];
        s8 ap1 = *(const s8*)&lP[wave][lr * 72 + 32 + qd * 8];
#pragma unroll
        for (int nt = 0; nt < 4; nt++) {
            s8 bv0 = *(const s8*)&lV[(nt * 16 + lr) * 72 + qd * 8];
            s8 bv1 = *(const s8*)&lV[(nt * 16 + lr) * 72 + 32 + qd * 8];
            o[nt] = __builtin_amdgcn_mfma_f32_16x16x32_bf16(ap0, bv0, o[nt], 0, 0, 0);
            o[nt] = __builtin_amdgcn_mfma_f32_16x16x32_bf16(ap1, bv1, o[nt], 0, 0, 0);
        }
        __syncthreads();   // protect lK/lV before next stage
    }

    // epilogue: X[b][l][h*64+d] = O/l
    const int b = bh >> 4, h = bh & 15;
#pragma unroll
    for (int nt = 0; nt < 4; nt++) {
#pragma unroll
        for (int ri = 0; ri < 4; ri++) {
            const int row = q0 + wave * 16 + qd * 4 + ri;
            const int col = h * 64 + nt * 16 + lr;
            const float v = o[nt][ri] / lrun[ri];
            X[((size_t)(b * Ls + row)) * Dd + col] = __float2bfloat16(v);
        }
    }
}

extern "C" void kernel_launch(void* const* d_in, const int* in_sizes, int n_in,
                              void* d_out, int out_size, void* d_ws, size_t ws_size,
                              hipStream_t stream) {
    const float* q_in = (const float*)d_in[0];
    const float* k_in = (const float*)d_in[1];
    const float* v_in = (const float*)d_in[2];
    const int*   mask = (const int*)d_in[3];
    const float* Wq = (const float*)d_in[4];  const float* bq = (const float*)d_in[5];
    const float* Wk = (const float*)d_in[6];  const float* bk = (const float*)d_in[7];
    const float* Wv = (const float*)d_in[8];  const float* bv = (const float*)d_in[9];
    const float* Wo = (const float*)d_in[10]; const float* bo = (const float*)d_in[11];
    float* out = (float*)d_out;   // reference output dtype = float32

    char* ws = (char*)d_ws;
    const size_t sz = (size_t)BHn * Ls * DK * sizeof(bf16);   // 16 MB each
    bf16* Qp = (bf16*)(ws);
    bf16* Kp = (bf16*)(ws + sz);
    bf16* Vt = (bf16*)(ws + 2 * sz);
    bf16* Xp = (bf16*)(ws + 3 * sz);
    unsigned long long* mb = (unsigned long long*)(ws + 4 * sz);

    dim3 gg(Mrows / 128, Dd / 128);
    gemm_nt_bias<1><<<gg, 256, 0, stream>>>(q_in, Wq, bq, Qp, Mrows, Dd, Dd);
    gemm_nt_bias<1><<<gg, 256, 0, stream>>>(k_in, Wk, bk, Kp, Mrows, Dd, Dd);
    gemm_nt_bias<2><<<gg, 256, 0, stream>>>(v_in, Wv, bv, Vt, Mrows, Dd, Dd);
    pack_mask<<<(Ls * Ls) / 256, 256, 0, stream>>>(mask, mb);
    attn<<<BHn * (Ls / 64), 256, 0, stream>>>(Qp, Kp, Vt, mb, Xp);
    gemm_nt_bias<0><<<gg, 256, 0, stream>>>(Xp, Wo, bo, out, Mrows, Dd, Dd);
}

// Round 6
// 494.113 us; speedup vs baseline: 1.1741x; 1.1741x over previous
//
#include <hip/hip_runtime.h>
#include <hip/hip_bf16.h>
#include <type_traits>

// MHA forward: B=4, L=2048, D=1024, H=16, dk=64.
// Inputs f32 (+ int32 mask), OUTPUT f32. Internals bf16 MFMA, fp32 accum.
// R6: pre-convert to bf16 + global_load_lds GEMM staging; attn rewritten in
// S^T orientation (per-lane softmax stats, P->PV via shfl, swizzled DMA tiles).

typedef __hip_bfloat16 bf16;
typedef __attribute__((ext_vector_type(8))) short s8;   // 8 bf16 (MFMA A/B frag)
typedef __attribute__((ext_vector_type(4))) short s4;   // 4 bf16 = 8B
typedef __attribute__((ext_vector_type(4))) float f4;   // MFMA C/D frag

constexpr int Bb = 4, Ls = 2048, Dd = 1024, Hh = 16, DK = 64;
constexpr int BHn = Bb * Hh;          // 64
constexpr int Mrows = Bb * Ls;        // 8192

typedef const __attribute__((address_space(1))) unsigned int* gas_t;
typedef __attribute__((address_space(3))) unsigned int* las_t;
__device__ __forceinline__ void dma16(const void* g, void* l) {
    __builtin_amdgcn_global_load_lds((gas_t)g, (las_t)l, 16, 0, 0);
}

__device__ __forceinline__ s8 ld8(const float* __restrict__ p) {
    const float4 a = *(const float4*)p;
    const float4 b = *(const float4*)(p + 4);
    union { bf16 h[8]; s8 v; } u;
    u.h[0] = __float2bfloat16(a.x); u.h[1] = __float2bfloat16(a.y);
    u.h[2] = __float2bfloat16(a.z); u.h[3] = __float2bfloat16(a.w);
    u.h[4] = __float2bfloat16(b.x); u.h[5] = __float2bfloat16(b.y);
    u.h[6] = __float2bfloat16(b.z); u.h[7] = __float2bfloat16(b.w);
    return u.v;
}
__device__ __forceinline__ void st1(bf16* p, float v)  { *p = __float2bfloat16(v); }
__device__ __forceinline__ void st1(float* p, float v) { *p = v; }

// ---------------- f32 -> bf16 convert (vectorized) ----------------
__global__ __launch_bounds__(256) void conv_bf16(
    const float* __restrict__ in, bf16* __restrict__ out, int n8)
{
    const int i = blockIdx.x * 256 + threadIdx.x;
    if (i < n8) *(s8*)&out[(size_t)i * 8] = ld8(in + (size_t)i * 8);
}

// ---------------- NT GEMM: out[m][n] = sum_k A[m][k]*W[n][k] + bias[n] ----------------
// MODE 0: out row-major [M][N] (f32 d_out) | MODE 1: headed [bh][l][d] | MODE 2: [bh][d][l]
template<int MODE, typename WT, typename OT>
__global__ __launch_bounds__(256) void gemm_nt(
    const bf16* __restrict__ A, const WT* __restrict__ W,
    const float* __restrict__ bias, OT* __restrict__ out,
    int M, int N, int K)
{
    __shared__ __align__(16) bf16 lA[128 * 32];
    __shared__ __align__(16) bf16 lB[128 * 32];
    const int tid  = threadIdx.x;
    const int wave = tid >> 6, lane = tid & 63;
    const int qd = lane >> 4, lr = lane & 15;
    const int wm = (wave & 1) * 64, wn = (wave >> 1) * 64;
    const int row0 = blockIdx.x * 128, col0 = blockIdx.y * 128;

    f4 acc[4][4] = {};

    // f32-W staging coords (only used when WT==float)
    const int c0 = tid, c1 = tid + 256;
    const int wr0 = c0 >> 2, wk0 = (c0 & 3) * 8;
    const int wr1 = c1 >> 2, wk1 = (c1 & 3) * 8;

    for (int kt = 0; kt < K; kt += 32) {
#pragma unroll
        for (int r = 0; r < 2; r++) {           // A via direct-to-LDS DMA
            const int s = r * 256 + tid;
            const int row = s >> 2, c = s & 3;
            dma16(A + (size_t)(row0 + row) * K + kt + c * 8, &lA[s * 8]);
        }
        if constexpr (std::is_same<WT, bf16>::value) {
#pragma unroll
            for (int r = 0; r < 2; r++) {
                const int s = r * 256 + tid;
                const int row = s >> 2, c = s & 3;
                dma16(W + (size_t)(col0 + row) * K + kt + c * 8, &lB[s * 8]);
            }
        } else {
            *(s8*)&lB[c0 * 8] = ld8(W + (size_t)(col0 + wr0) * K + kt + wk0);
            *(s8*)&lB[c1 * 8] = ld8(W + (size_t)(col0 + wr1) * K + kt + wk1);
        }
        __syncthreads();
        s8 af[4], bfm[4];
#pragma unroll
        for (int i = 0; i < 4; i++) af[i]  = *(const s8*)&lA[(wm + i * 16 + lr) * 32 + qd * 8];
#pragma unroll
        for (int j = 0; j < 4; j++) bfm[j] = *(const s8*)&lB[(wn + j * 16 + lr) * 32 + qd * 8];
#pragma unroll
        for (int i = 0; i < 4; i++)
#pragma unroll
            for (int j = 0; j < 4; j++)
                acc[i][j] = __builtin_amdgcn_mfma_f32_16x16x32_bf16(af[i], bfm[j], acc[i][j], 0, 0, 0);
        __syncthreads();
    }

    // epilogue: C/D layout col=lane&15, row=(lane>>4)*4+reg
#pragma unroll
    for (int j = 0; j < 4; j++) {
        const int colg = col0 + wn + j * 16 + lr;
        const float bv = bias[colg];
#pragma unroll
        for (int i = 0; i < 4; i++) {
            const int rowb = row0 + wm + i * 16 + qd * 4;
            if (MODE == 2) {
                const int b = rowb >> 11, l = rowb & (Ls - 1);
                const int h = colg >> 6, d = colg & (DK - 1);
                union { bf16 h4[4]; s4 v; } u;
#pragma unroll
                for (int ri = 0; ri < 4; ri++)
                    u.h4[ri] = __float2bfloat16(acc[i][j][ri] + bv);
                *(s4*)&((bf16*)out)[(((size_t)(b * Hh + h) * DK) + d) * Ls + l] = u.v;
            } else {
#pragma unroll
                for (int ri = 0; ri < 4; ri++) {
                    const int rowg = rowb + ri;
                    const float v = acc[i][j][ri] + bv;
                    size_t idx;
                    if (MODE == 0) {
                        idx = (size_t)rowg * N + colg;
                    } else {
                        const int b = rowg >> 11, l = rowg & (Ls - 1);
                        const int h = colg >> 6, d = colg & (DK - 1);
                        idx = (((size_t)(b * Hh + h) * Ls) + l) * DK + d;
                    }
                    st1(&out[idx], v);
                }
            }
        }
    }
}

// ---------------- mask bit-pack ----------------
__global__ __launch_bounds__(256) void pack_mask(
    const int* __restrict__ m, unsigned long long* __restrict__ bits)
{
    const int g = blockIdx.x * 256 + threadIdx.x;
    const unsigned long long b = __ballot(m[g] != 0);
    if ((threadIdx.x & 63) == 0) bits[g >> 6] = b;
}

// ---------------- flash attention, S^T orientation ----------------
// grid: BH*(L/64); block 256 = 4 waves; wave owns 16 q (cols of S^T), full dk=64.
// LDS tiles XOR-swizzled in 16B chunks: (row, chunk c) at [(row*8 + (c^(row&7)))*8].
__global__ __launch_bounds__(256) void attn(
    const bf16* __restrict__ Q, const bf16* __restrict__ K,
    const bf16* __restrict__ Vt, const unsigned long long* __restrict__ mbits,
    bf16* __restrict__ X)
{
    __shared__ __align__(16) bf16 lK[64 * 64];   // [k][d], swizzled
    __shared__ __align__(16) bf16 lV[64 * 64];   // [d][k], swizzled

    const int blk = blockIdx.x;
    const int bh = blk >> 5;
    const int q0 = (blk & 31) * 64;
    const int tid = threadIdx.x;
    const int wave = tid >> 6, lane = tid & 63;
    const int qd = lane >> 4, lr = lane & 15;
    const int qw0 = q0 + wave * 16;

    const bf16* Qb = Q  + (size_t)bh * Ls * DK;
    const bf16* Kb = K  + (size_t)bh * Ls * DK;
    const bf16* Vb = Vt + (size_t)bh * DK * Ls;

    // Q B-frags straight from global: lane lr -> q, elems qd*8+j -> d
    const s8 bq0 = *(const s8*)(Qb + (size_t)(qw0 + lr) * DK + qd * 8);
    const s8 bq1 = *(const s8*)(Qb + (size_t)(qw0 + lr) * DK + 32 + qd * 8);

    f4 o[4] = {};                      // O^T C-frags: row=d-in-tile, col=q
    float mrun = -3e38f, lrun = 0.f;   // per-lane (its q column), replicated over qd
    const float scale = 0.125f;        // dk^-0.5

    const int srcA = ((lane & 16) << 1) + lr;   // 32*(qd&1)+lr
    const bool hiSel = (lane & 32) != 0;        // qd>>1

    for (int kt = 0; kt < Ls / 64; ++kt) {
        const int k0 = kt * 64;
#pragma unroll
        for (int r = 0; r < 2; r++) {   // stage K,V tiles via DMA (swizzled)
            const int s = r * 256 + tid;
            const int row = s >> 3, cs = s & 7;
            const int c = cs ^ (row & 7);
            dma16(Kb + (size_t)(k0 + row) * DK + c * 8, &lK[s * 8]);
            dma16(Vb + (size_t)row * Ls + k0 + c * 8, &lV[s * 8]);
        }
        __syncthreads();

        // S^T = K_tile . Q^T : st[mt] has rows k=mt*16+qd*4+ri, col q=lr
        f4 st[4];
#pragma unroll
        for (int mt = 0; mt < 4; mt++) {
            const int rowk = mt * 16 + lr;
            const s8 ak0 = *(const s8*)&lK[(rowk * 8 + ((qd)     ^ (rowk & 7))) * 8];
            const s8 ak1 = *(const s8*)&lK[(rowk * 8 + ((4 + qd) ^ (rowk & 7))) * 8];
            f4 z = {};
            z = __builtin_amdgcn_mfma_f32_16x16x32_bf16(ak0, bq0, z, 0, 0, 0);
            z = __builtin_amdgcn_mfma_f32_16x16x32_bf16(ak1, bq1, z, 0, 0, 0);
            st[mt] = z;
        }

        // mask (fast path: whole wave all-ones -> fold scale into exp arg)
        const unsigned long long w = mbits[(size_t)(qw0 + lr) * (Ls / 64) + kt];
        float sc_eff = scale;
        if (__ballot(w == ~0ULL) != ~0ULL) {
            sc_eff = 1.f;
#pragma unroll
            for (int mt = 0; mt < 4; mt++)
#pragma unroll
                for (int ri = 0; ri < 4; ri++) {
                    const int kbit = mt * 16 + qd * 4 + ri;
                    float v = st[mt][ri] * scale;
                    if (!((w >> kbit) & 1ULL)) v = -1e9f;
                    st[mt][ri] = v;
                }
        }

        // online softmax over this lane's q column (16 in-reg + qd-group shfl)
        float tm = st[0][0];
#pragma unroll
        for (int mt = 0; mt < 4; mt++)
#pragma unroll
            for (int ri = 0; ri < 4; ri++) tm = fmaxf(tm, st[mt][ri]);
        tm *= sc_eff;
        tm = fmaxf(tm, __shfl_xor(tm, 16, 64));
        tm = fmaxf(tm, __shfl_xor(tm, 32, 64));
        const float mnew = fmaxf(mrun, tm);
        const float alpha = __expf(mrun - mnew);
        mrun = mnew;

        float rs = 0.f;
        unsigned pk[4][2];              // bf16-pair packs of P^T values (ri pairs)
#pragma unroll
        for (int mt = 0; mt < 4; mt++) {
#pragma unroll
            for (int u = 0; u < 2; u++) {
                const float p0 = __expf(fmaf(st[mt][2 * u],     sc_eff, -mnew));
                const float p1 = __expf(fmaf(st[mt][2 * u + 1], sc_eff, -mnew));
                rs += p0 + p1;
                union { bf16 h[2]; unsigned v; } t;
                t.h[0] = __float2bfloat16(p0);
                t.h[1] = __float2bfloat16(p1);
                pk[mt][u] = t.v;
            }
        }
        rs += __shfl_xor(rs, 16, 64);
        rs += __shfl_xor(rs, 32, 64);
        lrun = lrun * alpha + rs;

#pragma unroll
        for (int dt = 0; dt < 4; dt++)
#pragma unroll
            for (int ri = 0; ri < 4; ri++) o[dt][ri] *= alpha;

        // PV: O^T += V^T . P^T ; B-frag of P built via cross-lane shfl
#pragma unroll
        for (int h = 0; h < 2; h++) {
            const unsigned f0a = __shfl((int)pk[2 * h][0],     srcA, 64);
            const unsigned f0b = __shfl((int)pk[2 * h + 1][0], srcA, 64);
            const unsigned f1a = __shfl((int)pk[2 * h][1],     srcA, 64);
            const unsigned f1b = __shfl((int)pk[2 * h + 1][1], srcA, 64);
            const unsigned f2a = __shfl((int)pk[2 * h][0],     srcA + 16, 64);
            const unsigned f2b = __shfl((int)pk[2 * h + 1][0], srcA + 16, 64);
            const unsigned f3a = __shfl((int)pk[2 * h][1],     srcA + 16, 64);
            const unsigned f3b = __shfl((int)pk[2 * h + 1][1], srcA + 16, 64);
            union { unsigned u[4]; s8 v; } bp;
            bp.u[0] = hiSel ? f0b : f0a;
            bp.u[1] = hiSel ? f1b : f1a;
            bp.u[2] = hiSel ? f2b : f2a;
            bp.u[3] = hiSel ? f3b : f3a;
#pragma unroll
            for (int dt = 0; dt < 4; dt++) {
                const int rowd = dt * 16 + lr;
                const s8 av = *(const s8*)&lV[(rowd * 8 + ((h * 4 + qd) ^ (rowd & 7))) * 8];
                o[dt] = __builtin_amdgcn_mfma_f32_16x16x32_bf16(av, bp.v, o[dt], 0, 0, 0);
            }
        }
        __syncthreads();
    }

    // epilogue: X[b][q][head*64 + d] = O^T[d][q] / lrun
    const int b = bh >> 4, head = bh & 15;
    const float inv = 1.f / lrun;
    const int qrow = qw0 + lr;
#pragma unroll
    for (int dt = 0; dt < 4; dt++) {
        union { bf16 h4[4]; s4 v; } u;
#pragma unroll
        for (int ri = 0; ri < 4; ri++)
            u.h4[ri] = __float2bfloat16(o[dt][ri] * inv);
        *(s4*)&X[((size_t)(b * Ls + qrow)) * Dd + head * 64 + dt * 16 + qd * 4] = u.v;
    }
}

extern "C" void kernel_launch(void* const* d_in, const int* in_sizes, int n_in,
                              void* d_out, int out_size, void* d_ws, size_t ws_size,
                              hipStream_t stream) {
    const float* q_in = (const float*)d_in[0];
    const float* k_in = (const float*)d_in[1];
    const float* v_in = (const float*)d_in[2];
    const int*   mask = (const int*)d_in[3];
    const float* Wq = (const float*)d_in[4];  const float* bq = (const float*)d_in[5];
    const float* Wk = (const float*)d_in[6];  const float* bk = (const float*)d_in[7];
    const float* Wv = (const float*)d_in[8];  const float* bv = (const float*)d_in[9];
    const float* Wo = (const float*)d_in[10]; const float* bo = (const float*)d_in[11];
    float* out = (float*)d_out;

    char* ws = (char*)d_ws;
    const size_t sz = (size_t)BHn * Ls * DK * sizeof(bf16);   // 16.78 MB
    bf16* S0 = (bf16*)(ws);            // A-conv scratch, later Xp
    bf16* S1 = (bf16*)(ws + sz);       // Wv/Wk bf16 copies, later Qp
    bf16* S2 = (bf16*)(ws + 2 * sz);   // Kp, later Wo bf16 copy
    bf16* S3 = (bf16*)(ws + 3 * sz);   // Vt
    unsigned long long* mb = (unsigned long long*)(ws + 4 * sz);
    const int NW = Dd * Dd;            // 1M weight elems

    dim3 gg(Mrows / 128, Dd / 128);
    const int gA = (Mrows * Dd / 8 + 255) / 256;   // input conv grid
    const int gW = (NW / 8 + 255) / 256;           // weight conv grid

    // V (transposed-out), K, then Q (runtime f32 W); weights ride in dead slots
    conv_bf16<<<gA, 256, 0, stream>>>(v_in, S0, Mrows * Dd / 8);
    conv_bf16<<<gW, 256, 0, stream>>>(Wv, S1, NW / 8);
    gemm_nt<2, bf16, bf16><<<gg, 256, 0, stream>>>(S0, S1, bv, S3, Mrows, Dd, Dd);

    conv_bf16<<<gA, 256, 0, stream>>>(k_in, S0, Mrows * Dd / 8);
    conv_bf16<<<gW, 256, 0, stream>>>(Wk, S1 + NW, NW / 8);
    gemm_nt<1, bf16, bf16><<<gg, 256, 0, stream>>>(S0, S1 + NW, bk, S2, Mrows, Dd, Dd);

    conv_bf16<<<gA, 256, 0, stream>>>(q_in, S0, Mrows * Dd / 8);
    gemm_nt<1, float, bf16><<<gg, 256, 0, stream>>>(S0, Wq, bq, S1, Mrows, Dd, Dd);

    pack_mask<<<(Ls * Ls) / 256, 256, 0, stream>>>(mask, mb);
    attn<<<BHn * (Ls / 64), 256, 0, stream>>>(S1, S2, S3, mb, S0);

    conv_bf16<<<gW, 256, 0, stream>>>(Wo, S2, NW / 8);   // Kp dead after attn
    gemm_nt<0, bf16, float><<<gg, 256, 0, stream>>>(S0, S2, bo, out, Mrows, Dd, Dd);
}